// Round 1
// baseline (1464.576 us; speedup 1.0000x reference)
//
#include <hip/hip_runtime.h>

#define BB 4
#define NN 10000
#define EE 160000
#define HID 256
#define NHEAD 8

__device__ __forceinline__ unsigned fenc(float f) {
  unsigned u = __float_as_uint(f);
  return (u & 0x80000000u) ? ~u : (u | 0x80000000u);
}
__device__ __forceinline__ float fdec(unsigned u) {
  return __uint_as_float((u & 0x80000000u) ? (u ^ 0x80000000u) : ~u);
}

// ---- prep: What[k][h] = sum_d W_edge[k][h*32+d] * att_edge[h][d]  (64x8)
__global__ void k_prep(const float* __restrict__ We, const float* __restrict__ ae,
                       float* __restrict__ What) {
  int t = threadIdx.x;  // 512 threads
  int k = t >> 3, hh = t & 7;
  float s = 0.f;
#pragma unroll
  for (int d = 0; d < 32; ++d) s += We[k * HID + hh * 32 + d] * ae[hh * 32 + d];
  What[k * NHEAD + hh] = s;
}

// ---- node projection: h = nf @ W_node; s_src/s_dst per (node, head)
__global__ __launch_bounds__(256) void k_node(
    const float* __restrict__ nf, const float* __restrict__ Wn,
    const float* __restrict__ as_, const float* __restrict__ ad_,
    float* __restrict__ h, float* __restrict__ ssrc, float* __restrict__ sdst) {
  const int c = threadIdx.x;
  float w[128];
#pragma unroll
  for (int k = 0; k < 128; ++k) w[k] = Wn[k * HID + c];
  const float va = as_[c], vd = ad_[c];
  for (int bn = blockIdx.x; bn < BB * NN; bn += gridDim.x) {
    const float4* row = reinterpret_cast<const float4*>(nf + (size_t)bn * 128);
    float acc = 0.f;
#pragma unroll
    for (int k4 = 0; k4 < 32; ++k4) {
      float4 a = row[k4];
      acc += a.x * w[4 * k4] + a.y * w[4 * k4 + 1] + a.z * w[4 * k4 + 2] + a.w * w[4 * k4 + 3];
    }
    h[(size_t)bn * HID + c] = acc;
    float ps = acc * va, pd = acc * vd;
#pragma unroll
    for (int off = 16; off; off >>= 1) {
      ps += __shfl_xor(ps, off, 32);
      pd += __shfl_xor(pd, off, 32);
    }
    if ((c & 31) == 0) {
      ssrc[bn * NHEAD + (c >> 5)] = ps;
      sdst[bn * NHEAD + (c >> 5)] = pd;
    }
  }
}

// ---- edge logits + segment-max (32 edges per block, thread=(edge,head))
__global__ __launch_bounds__(256) void k_elogit(
    const float* __restrict__ ea, const int* __restrict__ ei,
    const float* __restrict__ What, const float* __restrict__ ssrc,
    const float* __restrict__ sdst, float* __restrict__ logits,
    unsigned* __restrict__ smax) {
  __shared__ float sea[32 * 65];
  __shared__ float sw[64 * NHEAD];
  const int t = threadIdx.x;
  sw[t] = What[t];
  sw[t + 256] = What[t + 256];
  const int g0 = blockIdx.x * 32;
  const float* base = ea + (size_t)g0 * 64;
#pragma unroll
  for (int j = 0; j < 8; ++j) {
    int f = t + j * 256;
    sea[(f >> 6) * 65 + (f & 63)] = base[f];
  }
  __syncthreads();
  const int il = t >> 3, hh = t & 7;
  const int g = g0 + il;
  float acc = 0.f;
#pragma unroll
  for (int k = 0; k < 64; ++k) acc += sea[il * 65 + k] * sw[k * NHEAD + hh];
  const int b = g / EE, e = g - b * EE;
  const int src = ei[e], dst = ei[EE + e];
  float lg = ssrc[((size_t)b * NN + src) * NHEAD + hh] +
             sdst[((size_t)b * NN + dst) * NHEAD + hh] + acc;
  lg = lg > 0.f ? lg : 0.2f * lg;
  logits[(size_t)g * NHEAD + hh] = lg;
  atomicMax(&smax[((size_t)b * NN + dst) * NHEAD + hh], fenc(lg));
}

// ---- edge aggregation: agg[b,dst,:] += ex*(h_src + ea@W_edge); ssum += ex
__global__ __launch_bounds__(256) void k_eagg(
    const float* __restrict__ ea, const int* __restrict__ ei,
    const float* __restrict__ We, const float* __restrict__ h,
    const float* __restrict__ logits, const unsigned* __restrict__ smax,
    float* __restrict__ ssum, float* __restrict__ agg, int per_block) {
  const int c = threadIdx.x;
  float w[64];
#pragma unroll
  for (int k = 0; k < 64; ++k) w[k] = We[k * HID + c];
  const int h8 = c >> 5;
  int g0 = blockIdx.x * per_block;
  int g1 = g0 + per_block;
  if (g1 > BB * EE) g1 = BB * EE;
  for (int g = g0; g < g1; ++g) {
    const float4* row = reinterpret_cast<const float4*>(ea + (size_t)g * 64);
    float acc = 0.f;
#pragma unroll
    for (int k4 = 0; k4 < 16; ++k4) {
      float4 a = row[k4];
      acc += a.x * w[4 * k4] + a.y * w[4 * k4 + 1] + a.z * w[4 * k4 + 2] + a.w * w[4 * k4 + 3];
    }
    const int b = g / EE, e = g - b * EE;
    const int src = ei[e], dst = ei[EE + e];
    const size_t nb = (size_t)b * NN + dst;
    const float lg = logits[(size_t)g * NHEAD + h8];
    const float m = fdec(smax[nb * NHEAD + h8]);
    const float ex = __expf(lg - m);
    const float hs = h[(((size_t)b * NN + src) << 8) + c];
    atomicAdd(&agg[(nb << 8) + c], ex * (hs + acc));
    if ((c & 31) == 0) atomicAdd(&ssum[nb * NHEAD + h8], ex);
  }
}

// ---- final: x = agg/ssum + nf@W_res; LayerNorm; ELU
__global__ __launch_bounds__(256) void k_final(
    const float* __restrict__ nf, const float* __restrict__ Wr,
    const float* __restrict__ agg, const float* __restrict__ ssum,
    const float* __restrict__ gam, const float* __restrict__ bet,
    float* __restrict__ out) {
  const int c = threadIdx.x;
  float w[128];
#pragma unroll
  for (int k = 0; k < 128; ++k) w[k] = Wr[k * HID + c];
  const float gg = gam[c], bb = bet[c];
  __shared__ float rs1[4], rs2[4];
  const int wid = c >> 6, lane = c & 63;
  for (int bn = blockIdx.x; bn < BB * NN; bn += gridDim.x) {
    const float4* row = reinterpret_cast<const float4*>(nf + (size_t)bn * 128);
    float acc = 0.f;
#pragma unroll
    for (int k4 = 0; k4 < 32; ++k4) {
      float4 a = row[k4];
      acc += a.x * w[4 * k4] + a.y * w[4 * k4 + 1] + a.z * w[4 * k4 + 2] + a.w * w[4 * k4 + 3];
    }
    const float sum = ssum[bn * NHEAD + (c >> 5)];
    const float sc = sum > 0.f ? 1.f / sum : 0.f;
    const float x = agg[(size_t)bn * HID + c] * sc + acc;
    float s1 = x, s2 = x * x;
#pragma unroll
    for (int off = 32; off; off >>= 1) {
      s1 += __shfl_xor(s1, off, 64);
      s2 += __shfl_xor(s2, off, 64);
    }
    if (lane == 0) { rs1[wid] = s1; rs2[wid] = s2; }
    __syncthreads();
    const float t1 = rs1[0] + rs1[1] + rs1[2] + rs1[3];
    const float t2 = rs2[0] + rs2[1] + rs2[2] + rs2[3];
    __syncthreads();
    const float mu = t1 * (1.f / HID);
    const float var = t2 * (1.f / HID) - mu * mu;
    float y = (x - mu) * rsqrtf(var + 1e-5f) * gg + bb;
    out[(size_t)bn * HID + c] = y > 0.f ? y : expm1f(y);
  }
}

extern "C" void kernel_launch(void* const* d_in, const int* in_sizes, int n_in,
                              void* d_out, int out_size, void* d_ws, size_t ws_size,
                              hipStream_t stream) {
  const float* nf   = (const float*)d_in[0];
  const int*   ei   = (const int*)d_in[1];
  const float* eatt = (const float*)d_in[2];
  const float* Wn   = (const float*)d_in[3];
  const float* We   = (const float*)d_in[4];
  const float* Wr   = (const float*)d_in[5];
  const float* as_  = (const float*)d_in[6];
  const float* ad_  = (const float*)d_in[7];
  const float* ae_  = (const float*)d_in[8];
  const float* gam  = (const float*)d_in[9];
  const float* bet  = (const float*)d_in[10];
  float* out = (float*)d_out;

  char* ws = (char*)d_ws;
  size_t off = 0;
  float* h      = (float*)(ws + off); off += (size_t)BB * NN * HID * 4;
  float* ssrc   = (float*)(ws + off); off += (size_t)BB * NN * NHEAD * 4;
  float* sdst   = (float*)(ws + off); off += (size_t)BB * NN * NHEAD * 4;
  float* What   = (float*)(ws + off); off += 64 * NHEAD * 4;
  float* logits = (float*)(ws + off); off += (size_t)BB * EE * NHEAD * 4;
  size_t zoff = off;
  unsigned* smax = (unsigned*)(ws + off); off += (size_t)BB * NN * NHEAD * 4;
  float* ssum    = (float*)(ws + off);    off += (size_t)BB * NN * NHEAD * 4;
  float* agg     = (float*)(ws + off);    off += (size_t)BB * NN * HID * 4;
  size_t zbytes = off - zoff;

  hipMemsetAsync(ws + zoff, 0, zbytes, stream);
  hipLaunchKernelGGL(k_prep, dim3(1), dim3(512), 0, stream, We, ae_, What);
  hipLaunchKernelGGL(k_node, dim3(2048), dim3(256), 0, stream, nf, Wn, as_, ad_, h, ssrc, sdst);
  hipLaunchKernelGGL(k_elogit, dim3(BB * EE / 32), dim3(256), 0, stream,
                     eatt, ei, What, ssrc, sdst, logits, smax);
  const int per_block = 250;
  hipLaunchKernelGGL(k_eagg, dim3(BB * EE / per_block), dim3(256), 0, stream,
                     eatt, ei, We, h, logits, smax, ssum, agg, per_block);
  hipLaunchKernelGGL(k_final, dim3(2048), dim3(256), 0, stream,
                     nf, Wr, agg, ssum, gam, bet, out);
}

// Round 2
// 577.846 us; speedup vs baseline: 2.5345x; 2.5345x over previous
//
#include <hip/hip_runtime.h>

#define BB 4
#define NN 10000
#define EE 160000
#define HID 256
#define NHEAD 8

// ---- prep: What[k][h] = sum_d W_edge[k][h*32+d] * att_edge[h][d]  (64x8)
__global__ void k_prep(const float* __restrict__ We, const float* __restrict__ ae,
                       float* __restrict__ What) {
  int t = threadIdx.x;  // 512 threads
  int k = t >> 3, hh = t & 7;
  float s = 0.f;
#pragma unroll
  for (int d = 0; d < 32; ++d) s += We[k * HID + hh * 32 + d] * ae[hh * 32 + d];
  What[k * NHEAD + hh] = s;
}

// ---- node projection: h = nf @ W_node; s_src/s_dst per (node, head)
__global__ __launch_bounds__(256) void k_node(
    const float* __restrict__ nf, const float* __restrict__ Wn,
    const float* __restrict__ as_, const float* __restrict__ ad_,
    float* __restrict__ h, float* __restrict__ ssrc, float* __restrict__ sdst) {
  const int c = threadIdx.x;
  float w[128];
#pragma unroll
  for (int k = 0; k < 128; ++k) w[k] = Wn[k * HID + c];
  const float va = as_[c], vd = ad_[c];
  for (int bn = blockIdx.x; bn < BB * NN; bn += gridDim.x) {
    const float4* row = reinterpret_cast<const float4*>(nf + (size_t)bn * 128);
    float acc = 0.f;
#pragma unroll
    for (int k4 = 0; k4 < 32; ++k4) {
      float4 a = row[k4];
      acc += a.x * w[4 * k4] + a.y * w[4 * k4 + 1] + a.z * w[4 * k4 + 2] + a.w * w[4 * k4 + 3];
    }
    h[(size_t)bn * HID + c] = acc;
    float ps = acc * va, pd = acc * vd;
#pragma unroll
    for (int off = 16; off; off >>= 1) {
      ps += __shfl_xor(ps, off, 32);
      pd += __shfl_xor(pd, off, 32);
    }
    if ((c & 31) == 0) {
      ssrc[bn * NHEAD + (c >> 5)] = ps;
      sdst[bn * NHEAD + (c >> 5)] = pd;
    }
  }
}

// ---- edge logits (no atomics now; max computed in k_agg via CSR)
__global__ __launch_bounds__(256) void k_elogit(
    const float* __restrict__ ea, const int* __restrict__ ei,
    const float* __restrict__ What, const float* __restrict__ ssrc,
    const float* __restrict__ sdst, float* __restrict__ logits) {
  __shared__ float sea[32 * 65];
  __shared__ float sw[64 * NHEAD];
  const int t = threadIdx.x;
  sw[t] = What[t];
  sw[t + 256] = What[t + 256];
  const int g0 = blockIdx.x * 32;
  const float* base = ea + (size_t)g0 * 64;
#pragma unroll
  for (int j = 0; j < 8; ++j) {
    int f = t + j * 256;
    sea[(f >> 6) * 65 + (f & 63)] = base[f];
  }
  __syncthreads();
  const int il = t >> 3, hh = t & 7;
  const int g = g0 + il;
  float acc = 0.f;
#pragma unroll
  for (int k = 0; k < 64; ++k) acc += sea[il * 65 + k] * sw[k * NHEAD + hh];
  const int b = g / EE, e = g - b * EE;
  const int src = ei[e], dst = ei[EE + e];
  float lg = ssrc[((size_t)b * NN + src) * NHEAD + hh] +
             sdst[((size_t)b * NN + dst) * NHEAD + hh] + acc;
  lg = lg > 0.f ? lg : 0.2f * lg;
  logits[(size_t)g * NHEAD + hh] = lg;
}

// ---- CSR build: histogram, scan, scatter
__global__ void k_hist(const int* __restrict__ ei, int* __restrict__ cnt) {
  int e = blockIdx.x * 256 + threadIdx.x;
  if (e < EE) atomicAdd(&cnt[ei[EE + e]], 1);
}

__global__ __launch_bounds__(1024) void k_scan(const int* __restrict__ cnt,
                                               int* __restrict__ off) {
  __shared__ int ls[1024];
  const int t = threadIdx.x;
  int own = 0;
  int deg[10];
  if (t < 1000) {
#pragma unroll
    for (int i = 0; i < 10; ++i) { deg[i] = cnt[t * 10 + i]; own += deg[i]; }
  }
  ls[t] = own;
  __syncthreads();
  for (int s = 1; s < 1024; s <<= 1) {
    int v = 0;
    if (t >= s) v = ls[t - s];
    __syncthreads();
    if (t >= s) ls[t] += v;
    __syncthreads();
  }
  if (t < 1000) {
    int start = ls[t] - own;
#pragma unroll
    for (int i = 0; i < 10; ++i) { off[t * 10 + i] = start; start += deg[i]; }
  }
  if (t == 0) off[NN] = EE;
}

__global__ void k_scatter(const int* __restrict__ ei, const int* __restrict__ off,
                          int* __restrict__ cur, int* __restrict__ perm,
                          int* __restrict__ esrc) {
  int e = blockIdx.x * 256 + threadIdx.x;
  if (e >= EE) return;
  int d = ei[EE + e];
  int pos = off[d] + atomicAdd(&cur[d], 1);
  perm[pos] = e;
  esrc[pos] = ei[e];
}

// ---- aggregation: wave = (batch=wid, node=blockIdx). No atomics.
//  u[b,node,c]   = sum_e ex[h]* h[b,src,c]   (+ z@We epilogue)
//  z[h][k]       = sum_e ex[h]* ea[b,e,k]    (registers, lane k holds z[*][k])
__global__ __launch_bounds__(256) void k_agg(
    const float* __restrict__ ea, const float* __restrict__ h,
    const float* __restrict__ logits, const int* __restrict__ off,
    const int* __restrict__ perm, const int* __restrict__ esrc,
    const float* __restrict__ We, float* __restrict__ u,
    float* __restrict__ ssum) {
  __shared__ float zsh[4][8 * 65];
  const int wid = threadIdx.x >> 6, l = threadIdx.x & 63;
  const int b = wid, node = blockIdx.x;
  const int start = off[node], end = off[node + 1];
  const int hq = l >> 3;   // head owning this lane's 4 u-channels
  const int hr = l & 7;    // head this lane tracks for logits/ex
  // pass A: per-head max
  float m = -3.0e38f;
  for (int i = start + (l >> 3); i < end; i += 8) {
    int e = perm[i];
    m = fmaxf(m, logits[((size_t)b * EE + e) * 8 + hr]);
  }
  m = fmaxf(m, __shfl_xor(m, 8));
  m = fmaxf(m, __shfl_xor(m, 16));
  m = fmaxf(m, __shfl_xor(m, 32));
  // pass B: accumulate
  float4 u4 = {0.f, 0.f, 0.f, 0.f};
  float z0 = 0.f, z1 = 0.f, z2 = 0.f, z3 = 0.f;
  float z4 = 0.f, z5 = 0.f, z6 = 0.f, z7 = 0.f;
  float ss = 0.f;
  for (int i = start; i < end; ++i) {
    const int e = perm[i];
    const int src = esrc[i];
    const float lg = logits[((size_t)b * EE + e) * 8 + hr];
    const float exl = __expf(lg - m);
    ss += exl;
    const float eal = ea[((size_t)b * EE + e) * 64 + l];
    const float e0 = __shfl(exl, 0), e1 = __shfl(exl, 1);
    const float e2 = __shfl(exl, 2), e3 = __shfl(exl, 3);
    const float e4 = __shfl(exl, 4), e5 = __shfl(exl, 5);
    const float e6 = __shfl(exl, 6), e7 = __shfl(exl, 7);
    z0 += e0 * eal; z1 += e1 * eal; z2 += e2 * eal; z3 += e3 * eal;
    z4 += e4 * eal; z5 += e5 * eal; z6 += e6 * eal; z7 += e7 * eal;
    const float exu = __shfl(exl, hq);
    const float4 hs =
        *reinterpret_cast<const float4*>(h + (((size_t)b * NN + src) << 8) + 4 * l);
    u4.x += exu * hs.x; u4.y += exu * hs.y;
    u4.z += exu * hs.z; u4.w += exu * hs.w;
  }
  // z epilogue: u4 += z[hq] @ We[:, 4l..4l+3]
  zsh[wid][0 * 65 + l] = z0; zsh[wid][1 * 65 + l] = z1;
  zsh[wid][2 * 65 + l] = z2; zsh[wid][3 * 65 + l] = z3;
  zsh[wid][4 * 65 + l] = z4; zsh[wid][5 * 65 + l] = z5;
  zsh[wid][6 * 65 + l] = z6; zsh[wid][7 * 65 + l] = z7;
  const float4* We4 = reinterpret_cast<const float4*>(We);  // [64][64]
#pragma unroll 8
  for (int k = 0; k < 64; ++k) {
    const float zk = zsh[wid][hq * 65 + k];
    const float4 wv = We4[k * 64 + l];
    u4.x += zk * wv.x; u4.y += zk * wv.y;
    u4.z += zk * wv.z; u4.w += zk * wv.w;
  }
  *reinterpret_cast<float4*>(u + (((size_t)b * NN + node) << 8) + 4 * l) = u4;
  if (l < 8) ssum[((size_t)b * NN + node) * 8 + l] = ss;
}

// ---- final: x = u/ssum + nf@W_res; LayerNorm; ELU
__global__ __launch_bounds__(256) void k_final(
    const float* __restrict__ nf, const float* __restrict__ Wr,
    const float* __restrict__ agg, const float* __restrict__ ssum,
    const float* __restrict__ gam, const float* __restrict__ bet,
    float* __restrict__ out) {
  const int c = threadIdx.x;
  float w[128];
#pragma unroll
  for (int k = 0; k < 128; ++k) w[k] = Wr[k * HID + c];
  const float gg = gam[c], bb = bet[c];
  __shared__ float rs1[4], rs2[4];
  const int wid = c >> 6, lane = c & 63;
  for (int bn = blockIdx.x; bn < BB * NN; bn += gridDim.x) {
    const float4* row = reinterpret_cast<const float4*>(nf + (size_t)bn * 128);
    float acc = 0.f;
#pragma unroll
    for (int k4 = 0; k4 < 32; ++k4) {
      float4 a = row[k4];
      acc += a.x * w[4 * k4] + a.y * w[4 * k4 + 1] + a.z * w[4 * k4 + 2] + a.w * w[4 * k4 + 3];
    }
    const float sum = ssum[bn * NHEAD + (c >> 5)];
    const float sc = sum > 0.f ? 1.f / sum : 0.f;
    const float x = agg[(size_t)bn * HID + c] * sc + acc;
    float s1 = x, s2 = x * x;
#pragma unroll
    for (int off = 32; off; off >>= 1) {
      s1 += __shfl_xor(s1, off, 64);
      s2 += __shfl_xor(s2, off, 64);
    }
    if (lane == 0) { rs1[wid] = s1; rs2[wid] = s2; }
    __syncthreads();
    const float t1 = rs1[0] + rs1[1] + rs1[2] + rs1[3];
    const float t2 = rs2[0] + rs2[1] + rs2[2] + rs2[3];
    __syncthreads();
    const float mu = t1 * (1.f / HID);
    const float var = t2 * (1.f / HID) - mu * mu;
    float y = (x - mu) * rsqrtf(var + 1e-5f) * gg + bb;
    out[(size_t)bn * HID + c] = y > 0.f ? y : expm1f(y);
  }
}

extern "C" void kernel_launch(void* const* d_in, const int* in_sizes, int n_in,
                              void* d_out, int out_size, void* d_ws, size_t ws_size,
                              hipStream_t stream) {
  const float* nf   = (const float*)d_in[0];
  const int*   ei   = (const int*)d_in[1];
  const float* eatt = (const float*)d_in[2];
  const float* Wn   = (const float*)d_in[3];
  const float* We   = (const float*)d_in[4];
  const float* Wr   = (const float*)d_in[5];
  const float* as_  = (const float*)d_in[6];
  const float* ad_  = (const float*)d_in[7];
  const float* ae_  = (const float*)d_in[8];
  const float* gam  = (const float*)d_in[9];
  const float* bet  = (const float*)d_in[10];
  float* out = (float*)d_out;

  char* ws = (char*)d_ws;
  size_t off_b = 0;
  float* h      = (float*)(ws + off_b); off_b += (size_t)BB * NN * HID * 4;
  float* ssrc   = (float*)(ws + off_b); size_t csr_off = off_b; off_b += (size_t)BB * NN * NHEAD * 4;
  float* sdst   = (float*)(ws + off_b); off_b += (size_t)BB * NN * NHEAD * 4;
  float* What   = (float*)(ws + off_b); off_b += 64 * NHEAD * 4;
  float* logits = (float*)(ws + off_b); off_b += (size_t)BB * EE * NHEAD * 4;
  float* u      = (float*)(ws + off_b); off_b += (size_t)BB * NN * HID * 4;
  float* ssum   = (float*)(ws + off_b); off_b += (size_t)BB * NN * NHEAD * 4;
  // CSR arrays alias ssrc/sdst (2.56 MB >= 1.44 MB) — used only AFTER k_elogit.
  char* csr = ws + csr_off;
  int* cnt  = (int*)(csr);
  int* offn = (int*)(csr + 40 * 1024);            // NN+1 ints
  int* cur  = (int*)(csr + 2 * 40 * 1024);
  int* perm = (int*)(csr + 3 * 40 * 1024);        // EE ints
  int* esrc = (int*)(csr + 3 * 40 * 1024 + (size_t)EE * 4);

  hipLaunchKernelGGL(k_prep, dim3(1), dim3(512), 0, stream, We, ae_, What);
  hipLaunchKernelGGL(k_node, dim3(2048), dim3(256), 0, stream, nf, Wn, as_, ad_, h, ssrc, sdst);
  hipLaunchKernelGGL(k_elogit, dim3(BB * EE / 32), dim3(256), 0, stream,
                     eatt, ei, What, ssrc, sdst, logits);
  hipMemsetAsync(csr, 0, 3 * 40 * 1024, stream);  // cnt, offn, cur
  hipLaunchKernelGGL(k_hist, dim3((EE + 255) / 256), dim3(256), 0, stream, ei, cnt);
  hipLaunchKernelGGL(k_scan, dim3(1), dim3(1024), 0, stream, cnt, offn);
  hipLaunchKernelGGL(k_scatter, dim3((EE + 255) / 256), dim3(256), 0, stream,
                     ei, offn, cur, perm, esrc);
  hipLaunchKernelGGL(k_agg, dim3(NN), dim3(256), 0, stream,
                     eatt, h, logits, offn, perm, esrc, We, u, ssum);
  hipLaunchKernelGGL(k_final, dim3(2048), dim3(256), 0, stream,
                     nf, Wr, u, ssum, gam, bet, out);
}